// Round 1
// baseline (4227.220 us; speedup 1.0000x reference)
//
#include <hip/hip_runtime.h>
#include <math.h>

// Problem constants (from reference setup_inputs)
#define B_ 256
#define S_ 512
#define K_ 20
#define D_ 256
#define NT 512   // threads per block: 8 waves

// One persistent workgroup per batch element b. State h[b] kept transposed in
// LDS ([d][k]) so the hU inner loop reads h rows as float4 broadcasts.
// mask[b,s] is uniform across the WG -> inactive steps are skipped entirely.
__global__ __launch_bounds__(NT, 1)
void rnn_entity_decoder(const float* __restrict__ es,
                        const int* __restrict__ mask,
                        const float* __restrict__ keys,
                        const float* __restrict__ U,
                        const float* __restrict__ V,
                        const float* __restrict__ W,
                        float* __restrict__ out) {
  __shared__ __align__(16) float sKeysT[D_][K_];  // keys[b] transposed [d][k]
  __shared__ __align__(16) float sHT[D_][K_];     // h transposed [d][k]
  __shared__ __align__(16) float sKV[K_][D_];     // keys[b] @ V, [k][e]
  __shared__ __align__(16) float sPart[K_][D_];   // hU partials, then upd
  __shared__ __align__(16) float sX[D_];          // x_t
  __shared__ float sXW1[D_];                      // xW partial from dhalf=1
  __shared__ float sGP[32][17];                   // gate partials (+1 pad)
  __shared__ float sG[K_];                        // sigmoid gate per k

  const int b    = blockIdx.x;
  const int t    = threadIdx.x;
  const int lane = t & 63;
  const int wave = t >> 6;
  const int e    = t & 255;   // output column / d-index
  const int dh   = t >> 8;    // 0 or 1: which half of the d-range

  // Load keys[b] transposed; init h = 0.
  for (int i = t; i < K_ * D_; i += NT) {
    int k = i >> 8, d = i & 255;
    sKeysT[d][k] = keys[(b * K_ + k) * D_ + d];
    sHT[d][k]    = 0.0f;
  }
  __syncthreads();

  // kV = keys[b] @ V  (time-invariant, once per WG).
  {
    float acc[10];
#pragma unroll
    for (int i = 0; i < 10; ++i) acc[i] = 0.0f;
    const int k0 = dh * 10;
    for (int d = 0; d < D_; ++d) {
      float v = V[d * D_ + e];
#pragma unroll
      for (int i = 0; i < 10; ++i)
        acc[i] = fmaf(sKeysT[d][k0 + i], v, acc[i]);
    }
#pragma unroll
    for (int i = 0; i < 10; ++i) sKV[k0 + i][e] = acc[i];
  }
  __syncthreads();

  for (int s = 0; s < S_; ++s) {
    // mask is uniform across the WG: skip inactive steps entirely.
    if (mask[b * S_ + s] == 0) continue;

    if (t < D_) sX[t] = es[(b * S_ + s) * D_ + t];
    __syncthreads();  // A: sX visible; prior step's sHT writes visible

    // Gate partials: g_logit[k] = sum_d x[d] * (h[k][d] + keys[k][d]).
    {
      const int gk  = t & 31;
      const int seg = t >> 5;  // 16 segments of 16 d's
      if (gk < K_) {
        float p = 0.0f;
        const int dbase = seg * 16;
#pragma unroll
        for (int j = 0; j < 16; ++j) {
          int d = dbase + j;
          p = fmaf(sX[d], sHT[d][gk] + sKeysT[d][gk], p);
        }
        sGP[gk][seg] = p;
      }
    }
    __syncthreads();  // B

    if (t < K_) {
      float z = 0.0f;
#pragma unroll
      for (int sgi = 0; sgi < 16; ++sgi) z += sGP[t][sgi];
      sG[t] = 1.0f / (1.0f + expf(-z));
    }

    // Main matmul: thread (e, dh) accumulates hU[k][e] and xW[e] over its
    // 128-wide d-slice. U/W column reads are coalesced across lanes (e).
    float acc[K_];
#pragma unroll
    for (int i = 0; i < K_; ++i) acc[i] = 0.0f;
    float xwp = 0.0f;
    {
      const float* __restrict__ Up = U + e;
      const float* __restrict__ Wp = W + e;
      const int d0 = dh * 128;
#pragma unroll 4
      for (int d = d0; d < d0 + 128; ++d) {
        float u  = Up[d * D_];
        float w  = Wp[d * D_];
        float xd = sX[d];
        xwp = fmaf(xd, w, xwp);
        const float4* h4 = (const float4*)(&sHT[d][0]);
        float hrow[20];
        *(float4*)(&hrow[0])  = h4[0];
        *(float4*)(&hrow[4])  = h4[1];
        *(float4*)(&hrow[8])  = h4[2];
        *(float4*)(&hrow[12]) = h4[3];
        *(float4*)(&hrow[16]) = h4[4];
#pragma unroll
        for (int k = 0; k < K_; ++k)
          acc[k] = fmaf(hrow[k], u, acc[k]);
      }
    }

    if (dh == 1) {
#pragma unroll
      for (int k = 0; k < K_; ++k) sPart[k][e] = acc[k];
      sXW1[e] = xwp;
    }
    __syncthreads();  // C: partials + sG visible

    if (dh == 0) {
      float xw = xwp + sXW1[e];
#pragma unroll
      for (int k = 0; k < K_; ++k) {
        float full = acc[k] + sPart[k][e] + sKV[k][e] + xw;
        float ht   = fmaxf(full, 0.0f);             // relu
        float upd  = fmaf(sG[k], ht, sHT[e][k]);    // h + g*h_tilda
        sPart[k][e] = upd;                          // own slot: no race
      }
    }
    __syncthreads();  // D: upd complete

    // L2-normalize each row k and write back into sHT (transposed).
    // Wave w owns rows {w, w+8, w+16}.
    for (int k = wave; k < K_; k += 8) {
      float v0 = sPart[k][lane];
      float v1 = sPart[k][lane + 64];
      float v2 = sPart[k][lane + 128];
      float v3 = sPart[k][lane + 192];
      float sum = (v0 * v0 + v1 * v1) + (v2 * v2 + v3 * v3);
#pragma unroll
      for (int off = 32; off >= 1; off >>= 1)
        sum += __shfl_xor(sum, off, 64);
      float scale = rsqrtf(fmaxf(sum, 1e-12f));
      sHT[lane][k]       = v0 * scale;
      sHT[lane + 64][k]  = v1 * scale;
      sHT[lane + 128][k] = v2 * scale;
      sHT[lane + 192][k] = v3 * scale;
    }
    __syncthreads();  // E: end of step
  }

  // Emit h_T: out[b][k][d] (fp32), coalesced on d.
  for (int i = t; i < K_ * D_; i += NT) {
    int k = i >> 8, d = i & 255;
    out[(b * K_ + k) * D_ + d] = sHT[d][k];
  }
}

extern "C" void kernel_launch(void* const* d_in, const int* in_sizes, int n_in,
                              void* d_out, int out_size, void* d_ws, size_t ws_size,
                              hipStream_t stream) {
  const float* es   = (const float*)d_in[0];
  const int*   mask = (const int*)d_in[1];
  const float* keys = (const float*)d_in[2];
  const float* U    = (const float*)d_in[3];
  const float* V    = (const float*)d_in[4];
  const float* W    = (const float*)d_in[5];
  float* out = (float*)d_out;
  rnn_entity_decoder<<<B_, NT, 0, stream>>>(es, mask, keys, U, V, W, out);
}

// Round 2
// 1570.581 us; speedup vs baseline: 2.6915x; 2.6915x over previous
//
#include <hip/hip_runtime.h>
#include <math.h>

#define B_ 256
#define S_ 512
#define K_ 20
#define D_ 256
#define NT 512
#define LDF 260   // f32 LDS row stride (pad vs 32-bank aliasing)
#define LDH 264   // bf16 LDS row stride (16B-aligned pad)

typedef __attribute__((ext_vector_type(8))) short short8;
typedef __attribute__((ext_vector_type(4))) short short4v;
typedef __attribute__((ext_vector_type(4))) float f32x4;

__device__ __forceinline__ unsigned short rne_bf16(float f) {
  unsigned u = __builtin_bit_cast(unsigned, f);
  u += 0x7FFFu + ((u >> 16) & 1u);
  return (unsigned short)(u >> 16);
}
__device__ __forceinline__ float bf16_to_f32(unsigned short h) {
  return __builtin_bit_cast(float, ((unsigned)h) << 16);
}

// ---------------- Phase A: XW[b,s,:] = es[b,s,:] @ W ----------------
// block: 32 rows x 256 cols; thread t owns column t, acc[32].
__global__ void xw_gemm(const float* __restrict__ es, const float* __restrict__ W,
                        float* __restrict__ XW) {
  __shared__ float xT[D_ * 36];  // [d][row], stride 36 (16B-aligned, spreads banks)
  const int t = threadIdx.x;
  const size_t row0 = (size_t)blockIdx.x * 32;
  for (int i = t; i < 32 * D_; i += 256) {
    int rr = i >> 8, d = i & 255;
    xT[d * 36 + rr] = es[row0 * D_ + i];  // read coalesced
  }
  __syncthreads();
  float acc[32];
#pragma unroll
  for (int r = 0; r < 32; ++r) acc[r] = 0.0f;
  const float* Wp = W + t;
#pragma unroll 2
  for (int d = 0; d < D_; ++d) {
    float wv = Wp[d * D_];  // coalesced across lanes; L2-resident
#pragma unroll
    for (int q = 0; q < 8; ++q) {
      f32x4 xq = *(const f32x4*)&xT[d * 36 + q * 4];  // broadcast within wave
      acc[q * 4 + 0] = fmaf(xq[0], wv, acc[q * 4 + 0]);
      acc[q * 4 + 1] = fmaf(xq[1], wv, acc[q * 4 + 1]);
      acc[q * 4 + 2] = fmaf(xq[2], wv, acc[q * 4 + 2]);
      acc[q * 4 + 3] = fmaf(xq[3], wv, acc[q * 4 + 3]);
    }
  }
  for (int r = 0; r < 32; ++r)
    XW[(row0 + r) * D_ + t] = acc[r];
}

// ---------------- Recurrent kernel: one persistent WG per batch b ----------------
// hU via mfma_f32_16x16x32_bf16 in split-bf16 (hi/lo) for fp32-class accuracy.
// Orientation: D[m=e][nCol=k] = sum_d A[e][d] * B[d][k], A = U^T (register
// frags), B = h^T (read from LDS bf16 hi/lo). C/D: col(k)=lane&15,
// row(e)=quad*4+reg -> each lane's 4 regs are 4 consecutive e at fixed k.
__global__ __launch_bounds__(NT, 1)
void rnn_rec(const float* __restrict__ es, const int* __restrict__ mask,
             const float* __restrict__ keys, const float* __restrict__ U,
             const float* __restrict__ V, const float* __restrict__ W,
             const float* __restrict__ XW, int use_xw,
             float* __restrict__ out) {
  __shared__ float sH[K_ * LDF];
  __shared__ float sKeys[K_ * LDF];
  __shared__ float sKV[K_ * LDF];
  __shared__ unsigned short sHhi[32 * LDH];  // rows 0..19 = h (or keys during kV); 20..31 zero pad
  __shared__ unsigned short sHlo[32 * LDH];
  __shared__ float sX[D_];
  __shared__ float sXW[D_];
  __shared__ float sXWp[2 * D_];
  __shared__ float sG[32];
  __shared__ int sMask[S_];

  const int b = blockIdx.x;
  const int t = threadIdx.x;
  const int w = t >> 6, lane = t & 63, quad = lane >> 4, n = lane & 15;

  // ---- setup ----
  for (int i = t; i < S_; i += NT) sMask[i] = mask[b * S_ + i];
  for (int i = t; i < K_ * D_; i += NT) {
    int k = i >> 8, d = i & 255;
    sKeys[k * LDF + d] = keys[(b * K_ + k) * D_ + d];
    sH[k * LDF + d] = 0.0f;
  }
  for (int i = t; i < 32 * LDH; i += NT) { sHhi[i] = 0; sHlo[i] = 0; }
  __syncthreads();
  // keys -> split bf16 (for the kV MFMA)
  for (int i = t; i < K_ * D_; i += NT) {
    int k = i >> 8, d = i & 255;
    float f = sKeys[k * LDF + d];
    unsigned short hi = rne_bf16(f);
    unsigned short lo = rne_bf16(f - bf16_to_f32(hi));
    sHhi[k * LDH + d] = hi; sHlo[k * LDH + d] = lo;
  }
  __syncthreads();

  short8 aHi[8][2], aLo[8][2];  // A-operand frags of M^T (M = V then U), register-resident

  auto load_A = [&](const float* __restrict__ M) {
#pragma unroll
    for (int kt = 0; kt < 8; ++kt)
#pragma unroll
      for (int et = 0; et < 2; ++et) {
        const int e = ((2 * w + et) << 4) + n;  // A row m = e
        const int d0 = kt * 32 + quad * 8;      // A col k-dim = d
        short8 h8, l8;
#pragma unroll
        for (int j = 0; j < 8; ++j) {
          float f = M[(d0 + j) * D_ + e];  // 16 lanes share a cache line
          unsigned short hi = rne_bf16(f);
          unsigned short lo = rne_bf16(f - bf16_to_f32(hi));
          h8[j] = (short)hi; l8[j] = (short)lo;
        }
        aHi[kt][et] = h8; aLo[kt][et] = l8;
      }
  };

  auto run_mfma = [&](f32x4 acc[2][2]) {
#pragma unroll
    for (int kt = 0; kt < 8; ++kt) {
      short8 bhi[2], blo[2];
#pragma unroll
      for (int ke = 0; ke < 2; ++ke) {
        const int off = (ke * 16 + n) * LDH + kt * 32 + quad * 8;  // B[k=row][d]
        bhi[ke] = *(const short8*)&sHhi[off];
        blo[ke] = *(const short8*)&sHlo[off];
      }
#pragma unroll
      for (int et = 0; et < 2; ++et)
#pragma unroll
        for (int ke = 0; ke < 2; ++ke) {
          acc[et][ke] = __builtin_amdgcn_mfma_f32_16x16x32_bf16(aHi[kt][et], bhi[ke], acc[et][ke], 0, 0, 0);
          acc[et][ke] = __builtin_amdgcn_mfma_f32_16x16x32_bf16(aLo[kt][et], bhi[ke], acc[et][ke], 0, 0, 0);
          acc[et][ke] = __builtin_amdgcn_mfma_f32_16x16x32_bf16(aHi[kt][et], blo[ke], acc[et][ke], 0, 0, 0);
        }
    }
  };

  // ---- kV = keys @ V (one-time, via the same MFMA path with A = V^T) ----
  load_A(V);
  {
    f32x4 acc[2][2] = {};
    run_mfma(acc);
#pragma unroll
    for (int et = 0; et < 2; ++et)
#pragma unroll
      for (int ke = 0; ke < 2; ++ke) {
        const int k = ke * 16 + n;
        if (k < K_) {
          const int e0 = ((2 * w + et) << 4) + quad * 4;
          *(f32x4*)&sKV[k * LDF + e0] = acc[et][ke];
        }
      }
  }
  __syncthreads();                    // all waves done reading keys frags
  for (int i = t; i < K_ * D_; i += NT) {  // h = 0 in bf16 mirrors
    int k = i >> 8, d = i & 255;
    sHhi[k * LDH + d] = 0; sHlo[k * LDH + d] = 0;
  }
  load_A(U);                          // A-frags now hold U^T for the recurrence
  __syncthreads();

  // ---- recurrence ----
  for (int s = 0; s < S_; ++s) {
    if (!sMask[s]) continue;  // WG-uniform: whole step skipped

    float xv = 0.0f, xwv = 0.0f;  // issue global loads first; hidden by MFMA phase
    if (t < D_) xv = es[((size_t)(b * S_ + s)) * D_ + t];
    else if (use_xw) xwv = XW[((size_t)(b * S_ + s)) * D_ + (t - D_)];

    f32x4 acc[2][2] = {};
    run_mfma(acc);  // reads only sHhi/sHlo (stable since prev B4)

    if (t < D_) sX[t] = xv;
    else sXW[t - D_] = xwv;
    __syncthreads();  // B1

    if (!use_xw) {  // fallback if ws too small: stream W per step
      const int e = t & 255, hf = t >> 8;
      float p = 0.0f;
      const float* Wp = W + e + hf * 128 * D_;
      for (int d = 0; d < 128; ++d)
        p = fmaf(sX[hf * 128 + d], Wp[d * D_], p);
      sXWp[hf * D_ + e] = p;
      __syncthreads();
      if (t < D_) sXW[t] = sXWp[t] + sXWp[D_ + t];
      __syncthreads();
    }

    // gate: g[k] = sigmoid(sum_d x[d]*(h[k][d]+keys[k][d]))
    {
      const int kk = t >> 4, j = t & 15;
      float gp = 0.0f;
      if (kk < K_) {
        const int d0 = j * 16;
#pragma unroll
        for (int q = 0; q < 4; ++q) {
          f32x4 xq = *(const f32x4*)&sX[d0 + q * 4];
          f32x4 hq = *(const f32x4*)&sH[kk * LDF + d0 + q * 4];
          f32x4 kq = *(const f32x4*)&sKeys[kk * LDF + d0 + q * 4];
#pragma unroll
          for (int i = 0; i < 4; ++i) gp = fmaf(xq[i], hq[i] + kq[i], gp);
        }
      }
      gp += __shfl_xor(gp, 1, 64);
      gp += __shfl_xor(gp, 2, 64);
      gp += __shfl_xor(gp, 4, 64);
      gp += __shfl_xor(gp, 8, 64);
      if (kk < K_ && j == 0) sG[kk] = 1.0f / (1.0f + expf(-gp));
    }
    __syncthreads();  // B2

    // epilogue: T = hU + kV + xw; relu; upd = h + g*T  (float4 on e)
#pragma unroll
    for (int et = 0; et < 2; ++et)
#pragma unroll
      for (int ke = 0; ke < 2; ++ke) {
        const int k = ke * 16 + n;
        if (k < K_) {
          const int e0 = ((2 * w + et) << 4) + quad * 4;
          f32x4 kv  = *(const f32x4*)&sKV[k * LDF + e0];
          f32x4 hv  = *(const f32x4*)&sH[k * LDF + e0];
          f32x4 xw4 = *(const f32x4*)&sXW[e0];
          const float g = sG[k];
          f32x4 a = acc[et][ke];
#pragma unroll
          for (int r = 0; r < 4; ++r) {
            float T = a[r] + kv[r] + xw4[r];
            T = fmaxf(T, 0.0f);
            hv[r] = fmaf(g, T, hv[r]);
          }
          *(f32x4*)&sH[k * LDF + e0] = hv;  // disjoint (k,e): no race
        }
      }
    __syncthreads();  // B3

    // l2-normalize rows; write fp32 + split-bf16 mirrors
    for (int k = w; k < K_; k += 8) {
      f32x4 v = *(const f32x4*)&sH[k * LDF + lane * 4];
      float ss = v[0] * v[0] + v[1] * v[1] + v[2] * v[2] + v[3] * v[3];
      ss += __shfl_xor(ss, 1, 64);
      ss += __shfl_xor(ss, 2, 64);
      ss += __shfl_xor(ss, 4, 64);
      ss += __shfl_xor(ss, 8, 64);
      ss += __shfl_xor(ss, 16, 64);
      ss += __shfl_xor(ss, 32, 64);
      const float sc = rsqrtf(fmaxf(ss, 1e-12f));
      v[0] *= sc; v[1] *= sc; v[2] *= sc; v[3] *= sc;
      *(f32x4*)&sH[k * LDF + lane * 4] = v;
      short4v hh, ll;
#pragma unroll
      for (int i = 0; i < 4; ++i) {
        unsigned short hi = rne_bf16(v[i]);
        unsigned short lo = rne_bf16(v[i] - bf16_to_f32(hi));
        hh[i] = (short)hi; ll[i] = (short)lo;
      }
      *(short4v*)&sHhi[k * LDH + lane * 4] = hh;
      *(short4v*)&sHlo[k * LDH + lane * 4] = ll;
    }
    __syncthreads();  // B4
  }

  // ---- emit h_T ----
  for (int i = t; i < K_ * D_; i += NT) {
    int k = i >> 8, d = i & 255;
    out[(b * K_ + k) * D_ + d] = sH[k * LDF + d];
  }
}

extern "C" void kernel_launch(void* const* d_in, const int* in_sizes, int n_in,
                              void* d_out, int out_size, void* d_ws, size_t ws_size,
                              hipStream_t stream) {
  const float* es   = (const float*)d_in[0];
  const int*   mask = (const int*)d_in[1];
  const float* keys = (const float*)d_in[2];
  const float* U    = (const float*)d_in[3];
  const float* V    = (const float*)d_in[4];
  const float* W    = (const float*)d_in[5];
  float* out = (float*)d_out;

  const size_t need = (size_t)B_ * S_ * D_ * sizeof(float);
  const int use_xw = (ws_size >= need) ? 1 : 0;
  float* XW = (float*)d_ws;
  if (use_xw) xw_gemm<<<(B_ * S_) / 32, 256, 0, stream>>>(es, W, XW);
  rnn_rec<<<B_, NT, 0, stream>>>(es, mask, keys, U, V, W, XW, use_xw, out);
}

// Round 4
// 1416.428 us; speedup vs baseline: 2.9844x; 1.1088x over previous
//
#include <hip/hip_runtime.h>
#include <math.h>

#define B_ 256
#define S_ 512
#define K_ 20
#define D_ 256
#define NT 512
#define LDF 260   // f32 LDS row stride
#define LDH 264   // bf16 LDS row stride (shorts)

typedef __attribute__((ext_vector_type(8))) short short8;
typedef __attribute__((ext_vector_type(4))) short short4v;
typedef __attribute__((ext_vector_type(4))) float f32x4;

__device__ __forceinline__ unsigned short rne_bf16(float f) {
  unsigned u = __builtin_bit_cast(unsigned, f);
  u += 0x7FFFu + ((u >> 16) & 1u);
  return (unsigned short)(u >> 16);
}
__device__ __forceinline__ float bf16_to_f32(unsigned short h) {
  return __builtin_bit_cast(float, ((unsigned)h) << 16);
}

// ---------------- Phase A: XW[b,s,:] = es[b,s,:] @ W (R2-proven fp32) -------
__global__ void xw_gemm(const float* __restrict__ es, const float* __restrict__ W,
                        float* __restrict__ XW) {
  __shared__ float xT[D_ * 36];
  const int t = threadIdx.x;
  const size_t row0 = (size_t)blockIdx.x * 32;
  for (int i = t; i < 32 * D_; i += 256) {
    int rr = i >> 8, d = i & 255;
    xT[d * 36 + rr] = es[row0 * D_ + i];
  }
  __syncthreads();
  float acc[32];
#pragma unroll
  for (int r = 0; r < 32; ++r) acc[r] = 0.0f;
  const float* Wp = W + t;
#pragma unroll 2
  for (int d = 0; d < D_; ++d) {
    float wv = Wp[d * D_];
#pragma unroll
    for (int q = 0; q < 8; ++q) {
      f32x4 xq = *(const f32x4*)&xT[d * 36 + q * 4];
      acc[q * 4 + 0] = fmaf(xq[0], wv, acc[q * 4 + 0]);
      acc[q * 4 + 1] = fmaf(xq[1], wv, acc[q * 4 + 1]);
      acc[q * 4 + 2] = fmaf(xq[2], wv, acc[q * 4 + 2]);
      acc[q * 4 + 3] = fmaf(xq[3], wv, acc[q * 4 + 3]);
    }
  }
  for (int r = 0; r < 32; ++r)
    XW[(row0 + r) * D_ + t] = acc[r];
}

// ---------------- Recurrence: one persistent WG per batch b -----------------
// R2's proven MFMA machinery (32-row zero-padded mirrors, unmasked reads)
// + lambda-folding (no normalize phase) + compacted active-step list.
__global__ __launch_bounds__(NT, 1)
void rnn_rec3(const float* __restrict__ es, const int* __restrict__ mask,
              const float* __restrict__ keys, const float* __restrict__ U,
              const float* __restrict__ V, const float* __restrict__ W,
              const float* __restrict__ XW, int use_xw, float* __restrict__ out) {
  __shared__ float sH[K_ * LDF];               // h_un fp32 (unnormalized)
  __shared__ float sKeys[K_ * LDF];
  __shared__ float sKV[K_ * LDF];
  __shared__ unsigned short sHhi[32 * LDH];    // split-bf16 mirror; rows 20..31 stay 0
  __shared__ unsigned short sHlo[32 * LDH];
  __shared__ float sX[D_], sXWb[D_], sXWp[2 * D_];
  __shared__ float sSq[K_][9];
  __shared__ float sLam[32];                   // per-row normalizer of sH
  __shared__ float sG[32];
  __shared__ short sAct[S_];
  __shared__ int   sNact;

  const int b = blockIdx.x, t = threadIdx.x;
  const int w = t >> 6, lane = t & 63, quad = lane >> 4, n = lane & 15;

  // ---- setup ----
  for (int i = t; i < K_ * D_; i += NT) {
    int k = i >> 8, d = i & 255;
    sKeys[k * LDF + d] = keys[(b * K_ + k) * D_ + d];
    sH[k * LDF + d] = 0.0f;
  }
  for (int i = t; i < 32 * LDH; i += NT) { sHhi[i] = 0; sHlo[i] = 0; }
  if (t < 32) sLam[t] = 1.0f;
  if (w == 0) {  // compact active step list (reads mask straight from global)
    int base = 0;
    for (int c = 0; c < 8; ++c) {
      int s = c * 64 + lane;
      int mv = mask[b * S_ + s];
      unsigned long long bal = __ballot(mv != 0);
      int pos = base + (int)__popcll(bal & ((1ull << lane) - 1ull));
      if (mv) sAct[pos] = (short)s;
      base += (int)__popcll(bal);
    }
    if (lane == 0) sNact = base;
  }
  __syncthreads();  // B0

  // keys -> split bf16 mirrors (rows 0..19); rows 20..31 remain zero
  for (int i = t; i < K_ * D_; i += NT) {
    int k = i >> 8, d = i & 255;
    float f = sKeys[k * LDF + d];
    unsigned short hi = rne_bf16(f);
    sHhi[k * LDH + d] = hi;
    sHlo[k * LDH + d] = rne_bf16(f - bf16_to_f32(hi));
  }
  __syncthreads();  // B1

  short8 aHi[8][2], aLo[8][2];  // register-resident A-frags (M^T)
  auto load_A = [&](const float* __restrict__ M) {
#pragma unroll
    for (int kt = 0; kt < 8; ++kt)
#pragma unroll
      for (int et = 0; et < 2; ++et) {
        const int e = ((2 * w + et) << 4) + n;
        const int d0 = kt * 32 + quad * 8;
        short8 h8, l8;
#pragma unroll
        for (int j = 0; j < 8; ++j) {
          float f = M[(d0 + j) * D_ + e];
          unsigned short hi = rne_bf16(f);
          h8[j] = (short)hi;
          l8[j] = (short)rne_bf16(f - bf16_to_f32(hi));
        }
        aHi[kt][et] = h8; aLo[kt][et] = l8;
      }
  };

  // R2-form: unmasked 32-row B-frag reads (rows 20..31 are true LDS zeros)
  auto run_mfma = [&](f32x4 acc[2][2]) {
#pragma unroll
    for (int kt = 0; kt < 8; ++kt) {
      short8 bhi[2], blo[2];
#pragma unroll
      for (int ke = 0; ke < 2; ++ke) {
        const int off = (ke * 16 + n) * LDH + kt * 32 + quad * 8;
        bhi[ke] = *(const short8*)&sHhi[off];
        blo[ke] = *(const short8*)&sHlo[off];
      }
#pragma unroll
      for (int et = 0; et < 2; ++et)
#pragma unroll
        for (int ke = 0; ke < 2; ++ke) {
          acc[et][ke] = __builtin_amdgcn_mfma_f32_16x16x32_bf16(aHi[kt][et], bhi[ke], acc[et][ke], 0, 0, 0);
          acc[et][ke] = __builtin_amdgcn_mfma_f32_16x16x32_bf16(aLo[kt][et], bhi[ke], acc[et][ke], 0, 0, 0);
          acc[et][ke] = __builtin_amdgcn_mfma_f32_16x16x32_bf16(aHi[kt][et], blo[ke], acc[et][ke], 0, 0, 0);
        }
    }
  };

  // ---- kV = keys @ V ----
  load_A(V);
  {
    f32x4 acc[2][2] = {};
    run_mfma(acc);
#pragma unroll
    for (int et = 0; et < 2; ++et)
#pragma unroll
      for (int ke = 0; ke < 2; ++ke) {
        const int k = ke * 16 + n;
        if (k < K_) {
          const int e0 = ((2 * w + et) << 4) + quad * 4;
          *(f32x4*)&sKV[k * LDF + e0] = acc[et][ke];
        }
      }
  }
  __syncthreads();  // B2: keys-frag reads done
  const int nAct = sNact;
  for (int i = t; i < K_ * D_; i += NT) {  // h_un = 0 mirrors (pads already 0)
    int k = i >> 8, d = i & 255;
    sHhi[k * LDH + d] = 0; sHlo[k * LDH + d] = 0;
  }
  load_A(U);
  {  // prologue: stage x/xw for the first active step
    float xn = 0.0f, xwn = 0.0f;
    if (nAct > 0) {
      int s0 = sAct[0];
      if (t < 256) xn = es[((size_t)(b * S_ + s0)) * D_ + t];
      else if (use_xw) xwn = XW[((size_t)(b * S_ + s0)) * D_ + (t - 256)];
    }
    if (t < 256) sX[t] = xn; else sXWb[t - 256] = xwn;
  }
  __syncthreads();  // B3

  // ---- recurrence over active steps ----
  for (int i = 0; i < nAct; ++i) {
    if (!use_xw) {  // fallback: stream W per step
      const int e = t & 255, hf = t >> 8;
      float p = 0.0f;
      const float* Wp = W + hf * 128 * D_ + e;
      for (int d = 0; d < 128; ++d)
        p = fmaf(sX[hf * 128 + d], Wp[d * D_], p);
      sXWp[hf * 256 + e] = p;
      __syncthreads();
      if (t < 256) sXWb[t] = sXWp[t] + sXWp[256 + t];
      __syncthreads();
    }

    // prefetch next active step's x/xw (consumed in tail region)
    float xn = 0.0f, xwn = 0.0f;
    if (i + 1 < nAct) {
      int sn = sAct[i + 1];
      if (t < 256) xn = es[((size_t)(b * S_ + sn)) * D_ + t];
      else if (use_xw) xwn = XW[((size_t)(b * S_ + sn)) * D_ + (t - 256)];
    }

    // gate: logit[k] = lam[k]*(x . h_un[k]) + (x . keys[k])
    {
      const int kk = t >> 4, j = t & 15;
      if (kk < K_) {
        const int d0 = j * 16;
        float p1 = 0.0f, p2 = 0.0f;
#pragma unroll
        for (int q = 0; q < 4; ++q) {
          f32x4 xq = *(const f32x4*)&sX[d0 + q * 4];
          f32x4 hq = *(const f32x4*)&sH[kk * LDF + d0 + q * 4];
          f32x4 kq = *(const f32x4*)&sKeys[kk * LDF + d0 + q * 4];
#pragma unroll
          for (int r = 0; r < 4; ++r) {
            p1 = fmaf(xq[r], hq[r], p1);
            p2 = fmaf(xq[r], kq[r], p2);
          }
        }
        p1 += __shfl_xor(p1, 1, 64); p2 += __shfl_xor(p2, 1, 64);
        p1 += __shfl_xor(p1, 2, 64); p2 += __shfl_xor(p2, 2, 64);
        p1 += __shfl_xor(p1, 4, 64); p2 += __shfl_xor(p2, 4, 64);
        p1 += __shfl_xor(p1, 8, 64); p2 += __shfl_xor(p2, 8, 64);
        if (j == 0) {
          float z = sLam[kk] * p1 + p2;
          sG[kk] = 1.0f / (1.0f + expf(-z));
        }
      }
    }

    f32x4 acc[2][2] = {};
    run_mfma(acc);
    __syncthreads();  // R1

    // epilogue: u = lam*h_un + g*relu(lam*acc + kV + xW); write state from regs
    {
      float psq0 = 0.0f, psq1 = 0.0f;
#pragma unroll
      for (int et = 0; et < 2; ++et)
#pragma unroll
        for (int ke = 0; ke < 2; ++ke) {
          const int k = ke * 16 + n;
          if (k < K_) {
            const int e0 = ((2 * w + et) << 4) + quad * 4;
            f32x4 kv = *(const f32x4*)&sKV[k * LDF + e0];
            f32x4 hv = *(const f32x4*)&sH[k * LDF + e0];
            f32x4 xw4 = *(const f32x4*)&sXWb[e0];
            const float g = sG[k], lm = sLam[k];
            f32x4 u;
            short4v hh, ll;
#pragma unroll
            for (int r = 0; r < 4; ++r) {
              float T = fmaxf(fmaf(lm, acc[et][ke][r], kv[r] + xw4[r]), 0.0f);
              u[r] = fmaf(g, T, lm * hv[r]);
              if (ke == 0) psq0 = fmaf(u[r], u[r], psq0);
              else         psq1 = fmaf(u[r], u[r], psq1);
              unsigned short hi = rne_bf16(u[r]);
              hh[r] = (short)hi;
              ll[r] = (short)rne_bf16(u[r] - bf16_to_f32(hi));
            }
            *(f32x4*)&sH[k * LDF + e0] = u;
            *(short4v*)&sHhi[k * LDH + e0] = hh;
            *(short4v*)&sHlo[k * LDH + e0] = ll;
          }
        }
      float p0 = psq0, p1v = psq1;
      p0 += __shfl_xor(p0, 16, 64); p1v += __shfl_xor(p1v, 16, 64);
      p0 += __shfl_xor(p0, 32, 64); p1v += __shfl_xor(p1v, 32, 64);
      if (quad == 0) {
        sSq[n][w] = p0;
        if (n < 4) sSq[16 + n][w] = p1v;
      }
    }
    __syncthreads();  // R2

    // tail: new lambda + stage next x/xw
    if (t < K_) {
      float ss = 0.0f;
#pragma unroll
      for (int ww = 0; ww < 8; ++ww) ss += sSq[t][ww];
      sLam[t] = rsqrtf(fmaxf(ss, 1e-12f));
    }
    if (t < 256) sX[t] = xn; else sXWb[t - 256] = xwn;
    __syncthreads();  // R0
  }

  // ---- emit h_T = lam * h_un ----
  for (int i = t; i < K_ * D_; i += NT) {
    int k = i >> 8, d = i & 255;
    out[(b * K_ + k) * D_ + d] = sLam[k] * sH[k * LDF + d];
  }
}

extern "C" void kernel_launch(void* const* d_in, const int* in_sizes, int n_in,
                              void* d_out, int out_size, void* d_ws, size_t ws_size,
                              hipStream_t stream) {
  const float* es   = (const float*)d_in[0];
  const int*   mask = (const int*)d_in[1];
  const float* keys = (const float*)d_in[2];
  const float* U    = (const float*)d_in[3];
  const float* V    = (const float*)d_in[4];
  const float* W    = (const float*)d_in[5];
  float* out = (float*)d_out;

  const size_t need = (size_t)B_ * S_ * D_ * sizeof(float);
  const int use_xw = (ws_size >= need) ? 1 : 0;
  float* XW = (float*)d_ws;
  if (use_xw) xw_gemm<<<(B_ * S_) / 32, 256, 0, stream>>>(es, W, XW);
  rnn_rec3<<<B_, NT, 0, stream>>>(es, mask, keys, U, V, W, XW, use_xw, out);
}

// Round 5
// 1339.034 us; speedup vs baseline: 3.1569x; 1.0578x over previous
//
#include <hip/hip_runtime.h>
#include <math.h>

#define B_ 256
#define S_ 512
#define K_ 20
#define D_ 256
#define NT 512
#define LDH 264   // bf16 LDS row stride (shorts)

typedef __attribute__((ext_vector_type(8))) short short8;
typedef __attribute__((ext_vector_type(4))) short short4v;
typedef __attribute__((ext_vector_type(4))) float f32x4;

__device__ __forceinline__ unsigned short rne_bf16(float f) {
  unsigned u = __builtin_bit_cast(unsigned, f);
  u += 0x7FFFu + ((u >> 16) & 1u);
  return (unsigned short)(u >> 16);
}
__device__ __forceinline__ float bf16_to_f32(unsigned short h) {
  return __builtin_bit_cast(float, ((unsigned)h) << 16);
}

// ---------------- Phase A: XW[b,s,:] = es[b,s,:] @ W (R2/R4-proven) ---------
__global__ void xw_gemm(const float* __restrict__ es, const float* __restrict__ W,
                        float* __restrict__ XW) {
  __shared__ float xT[D_ * 36];
  const int t = threadIdx.x;
  const size_t row0 = (size_t)blockIdx.x * 32;
  for (int i = t; i < 32 * D_; i += 256) {
    int rr = i >> 8, d = i & 255;
    xT[d * 36 + rr] = es[row0 * D_ + i];
  }
  __syncthreads();
  float acc[32];
#pragma unroll
  for (int r = 0; r < 32; ++r) acc[r] = 0.0f;
  const float* Wp = W + t;
#pragma unroll 2
  for (int d = 0; d < D_; ++d) {
    float wv = Wp[d * D_];
#pragma unroll
    for (int q = 0; q < 8; ++q) {
      f32x4 xq = *(const f32x4*)&xT[d * 36 + q * 4];
      acc[q * 4 + 0] = fmaf(xq[0], wv, acc[q * 4 + 0]);
      acc[q * 4 + 1] = fmaf(xq[1], wv, acc[q * 4 + 1]);
      acc[q * 4 + 2] = fmaf(xq[2], wv, acc[q * 4 + 2]);
      acc[q * 4 + 3] = fmaf(xq[3], wv, acc[q * 4 + 3]);
    }
  }
  for (int r = 0; r < 32; ++r)
    XW[(row0 + r) * D_ + t] = acc[r];
}

// ---------------- Recurrence: register-resident state, 2 barriers/step -----
// hReg/kvReg/kReg hold h_un/kV/keys in MFMA C/D layout (k=ke*16+n,
// e=32w+16et+4quad+r). Gate merged into previous epilogue: psq/pxh/pxk
// reduced together; 20 threads compute lam+g at the top of the next step.
__global__ __launch_bounds__(NT, 2)
void rnn_rec5(const float* __restrict__ es, const int* __restrict__ mask,
              const float* __restrict__ keys, const float* __restrict__ U,
              const float* __restrict__ V, const float* __restrict__ W,
              const float* __restrict__ XW, float* __restrict__ out) {
  __shared__ unsigned short sHhi[32 * LDH];  // rows 0..19 = state, 20..31 stay 0
  __shared__ unsigned short sHlo[32 * LDH];
  __shared__ float sX[D_];                   // x_{i+1} (gate source)
  __shared__ float sXWb[D_];                 // xW_i (epilogue source)
  __shared__ float sRed[3][K_][9];           // psq / pxh / pxk partials per wave
  __shared__ float sLam[32], sG[32];
  __shared__ short sAct[S_];
  __shared__ int   sNact;

  const int b = blockIdx.x, t = threadIdx.x;
  const int w = t >> 6, lane = t & 63, quad = lane >> 4, n = lane & 15;
  const int e0a = (w << 5) + quad * 4;  // et=0 e-base; et adds 16

  // ---- P0: zero mirrors + sRed[0..1]; compact active steps ----
  for (int i = t; i < 32 * LDH; i += NT) { sHhi[i] = 0; sHlo[i] = 0; }
  if (t < 2 * K_ * 9) ((float*)sRed)[t] = 0.0f;
  if (w == 0) {
    int base = 0;
    for (int c = 0; c < 8; ++c) {
      int s = c * 64 + lane;
      int mv = mask[b * S_ + s];
      unsigned long long bal = __ballot(mv != 0);
      int pos = base + (int)__popcll(bal & ((1ull << lane) - 1ull));
      if (mv) sAct[pos] = (short)s;
      base += (int)__popcll(bal);
    }
    if (lane == 0) sNact = base;
  }
  __syncthreads();  // P0

  // keys -> split-bf16 mirrors (rows 0..19)
  for (int i = t; i < K_ * D_; i += NT) {
    int k = i >> 8, d = i & 255;
    float f = keys[(b * K_ + k) * D_ + d];
    unsigned short hi = rne_bf16(f);
    sHhi[k * LDH + d] = hi;
    sHlo[k * LDH + d] = rne_bf16(f - bf16_to_f32(hi));
  }
  // kReg: keys in C/D layout (OOB rows k>=20 -> 0)
  f32x4 kReg[2][2];
#pragma unroll
  for (int et = 0; et < 2; ++et)
#pragma unroll
    for (int ke = 0; ke < 2; ++ke) {
      const int k = ke * 16 + n;
#pragma unroll
      for (int r = 0; r < 4; ++r)
        kReg[et][ke][r] = (k < K_) ? keys[(size_t)(b * K_ + k) * D_ + e0a + 16 * et + r] : 0.0f;
    }

  short8 aHi[8][2], aLo[8][2];  // register-resident A-frags (M^T)
  auto load_A = [&](const float* __restrict__ M) {
#pragma unroll
    for (int kt = 0; kt < 8; ++kt)
#pragma unroll
      for (int et = 0; et < 2; ++et) {
        const int e = ((2 * w + et) << 4) + n;
        const int d0 = kt * 32 + quad * 8;
        short8 h8, l8;
#pragma unroll
        for (int j = 0; j < 8; ++j) {
          float f = M[(d0 + j) * D_ + e];
          unsigned short hi = rne_bf16(f);
          h8[j] = (short)hi;
          l8[j] = (short)rne_bf16(f - bf16_to_f32(hi));
        }
        aHi[kt][et] = h8; aLo[kt][et] = l8;
      }
  };
  // R4-proven: unmasked 32-row B-frag reads (rows 20..31 true LDS zeros)
  auto run_mfma = [&](f32x4 acc[2][2]) {
#pragma unroll
    for (int kt = 0; kt < 8; ++kt) {
      short8 bhi[2], blo[2];
#pragma unroll
      for (int ke = 0; ke < 2; ++ke) {
        const int off = (ke * 16 + n) * LDH + kt * 32 + quad * 8;
        bhi[ke] = *(const short8*)&sHhi[off];
        blo[ke] = *(const short8*)&sHlo[off];
      }
#pragma unroll
      for (int et = 0; et < 2; ++et)
#pragma unroll
        for (int ke = 0; ke < 2; ++ke) {
          acc[et][ke] = __builtin_amdgcn_mfma_f32_16x16x32_bf16(aHi[kt][et], bhi[ke], acc[et][ke], 0, 0, 0);
          acc[et][ke] = __builtin_amdgcn_mfma_f32_16x16x32_bf16(aLo[kt][et], bhi[ke], acc[et][ke], 0, 0, 0);
          acc[et][ke] = __builtin_amdgcn_mfma_f32_16x16x32_bf16(aHi[kt][et], blo[ke], acc[et][ke], 0, 0, 0);
        }
    }
  };

  load_A(V);
  __syncthreads();  // P1: keys mirrors ready

  f32x4 kvReg[2][2] = {};
  run_mfma(kvReg);  // kV = keys @ V, kept in registers forever
  __syncthreads();  // P2: keys-mirror reads done

  for (int i = t; i < K_ * D_; i += NT) {  // h_un = 0 mirrors
    int k = i >> 8, d = i & 255;
    sHhi[k * LDH + d] = 0; sHlo[k * LDH + d] = 0;
  }
  load_A(U);
  f32x4 hReg[2][2] = {};
  const int nAct = sNact;
  if (t < D_ && nAct > 0) sX[t] = es[(size_t)(b * S_ + sAct[0]) * D_ + t];
  __syncthreads();  // P3

  // mini-epilogue: pxk = x_0 . keys  (psq=pxh=0 already zeroed)
  {
    float p0 = 0.0f, p1 = 0.0f;
#pragma unroll
    for (int et = 0; et < 2; ++et) {
      f32x4 xq = *(const f32x4*)&sX[e0a + 16 * et];
#pragma unroll
      for (int r = 0; r < 4; ++r) {
        p0 = fmaf(xq[r], kReg[et][0][r], p0);
        p1 = fmaf(xq[r], kReg[et][1][r], p1);
      }
    }
    p0 += __shfl_xor(p0, 16, 64); p0 += __shfl_xor(p0, 32, 64);
    p1 += __shfl_xor(p1, 16, 64); p1 += __shfl_xor(p1, 32, 64);
    if (quad == 0) {
      sRed[2][n][w] = p0;
      if (n < 4) sRed[2][16 + n][w] = p1;
    }
  }
  __syncthreads();  // P4 (acts as the loop's R2)

  // ---- recurrence over active steps ----
  for (int i = 0; i < nAct; ++i) {
    // issue global prefetch first (hidden under MFMA region)
    float xv = 0.0f, xwv = 0.0f;
    if (t < D_) {
      if (i + 1 < nAct) xv = es[(size_t)(b * S_ + sAct[i + 1]) * D_ + t];
    } else {
      xwv = XW[(size_t)(b * S_ + sAct[i]) * D_ + (t - D_)];
    }
    // tail: 20 threads of wave 0 compute lam_{i-1} and g_i
    if (t < K_) {
      float ss = 0.0f, xh = 0.0f, xk = 0.0f;
#pragma unroll
      for (int j = 0; j < 8; ++j) {
        ss += sRed[0][t][j]; xh += sRed[1][t][j]; xk += sRed[2][t][j];
      }
      float lam = rsqrtf(fmaxf(ss, 1e-12f));
      sLam[t] = lam;
      sG[t] = 1.0f / (1.0f + expf(-(lam * xh + xk)));
    }
    f32x4 acc[2][2] = {};
    run_mfma(acc);  // u_{i-1} @ U
    if (t < D_) sX[t] = xv; else sXWb[t - D_] = xwv;
    __syncthreads();  // R1

    // epilogue: all register math; write mirrors + merged reduction
    const float lm0 = sLam[n], g0 = sG[n];
    const float lm1 = (n < 4) ? sLam[16 + n] : 0.0f;
    const float g1 = (n < 4) ? sG[16 + n] : 0.0f;
    float psq0 = 0.0f, psq1 = 0.0f, pxh0 = 0.0f, pxh1 = 0.0f, pxk0 = 0.0f, pxk1 = 0.0f;
#pragma unroll
    for (int et = 0; et < 2; ++et) {
      const int e0 = e0a + 16 * et;
      f32x4 xw4 = *(const f32x4*)&sXWb[e0];
      f32x4 xn4 = *(const f32x4*)&sX[e0];
      {  // ke = 0 (k = n, always valid)
        f32x4 u; short4v hh, ll;
#pragma unroll
        for (int r = 0; r < 4; ++r) {
          float T = fmaxf(fmaf(lm0, acc[et][0][r], kvReg[et][0][r] + xw4[r]), 0.0f);
          float uv = fmaf(g0, T, lm0 * hReg[et][0][r]);
          u[r] = uv;
          psq0 = fmaf(uv, uv, psq0);
          pxh0 = fmaf(xn4[r], uv, pxh0);
          pxk0 = fmaf(xn4[r], kReg[et][0][r], pxk0);
          unsigned short hi = rne_bf16(uv);
          hh[r] = (short)hi;
          ll[r] = (short)rne_bf16(uv - bf16_to_f32(hi));
        }
        hReg[et][0] = u;
        *(short4v*)&sHhi[n * LDH + e0] = hh;
        *(short4v*)&sHlo[n * LDH + e0] = ll;
      }
      {  // ke = 1 (k = 16+n, valid for n<4; lm1=g1=0 -> u stays 0 otherwise)
        f32x4 u; short4v hh, ll;
#pragma unroll
        for (int r = 0; r < 4; ++r) {
          float T = fmaxf(fmaf(lm1, acc[et][1][r], kvReg[et][1][r] + xw4[r]), 0.0f);
          float uv = fmaf(g1, T, lm1 * hReg[et][1][r]);
          u[r] = uv;
          psq1 = fmaf(uv, uv, psq1);
          pxh1 = fmaf(xn4[r], uv, pxh1);
          pxk1 = fmaf(xn4[r], kReg[et][1][r], pxk1);
          unsigned short hi = rne_bf16(uv);
          hh[r] = (short)hi;
          ll[r] = (short)rne_bf16(uv - bf16_to_f32(hi));
        }
        hReg[et][1] = u;
        if (n < 4) {
          *(short4v*)&sHhi[(16 + n) * LDH + e0] = hh;
          *(short4v*)&sHlo[(16 + n) * LDH + e0] = ll;
        }
      }
    }
    psq0 += __shfl_xor(psq0, 16, 64); psq0 += __shfl_xor(psq0, 32, 64);
    pxh0 += __shfl_xor(pxh0, 16, 64); pxh0 += __shfl_xor(pxh0, 32, 64);
    pxk0 += __shfl_xor(pxk0, 16, 64); pxk0 += __shfl_xor(pxk0, 32, 64);
    psq1 += __shfl_xor(psq1, 16, 64); psq1 += __shfl_xor(psq1, 32, 64);
    pxh1 += __shfl_xor(pxh1, 16, 64); pxh1 += __shfl_xor(pxh1, 32, 64);
    pxk1 += __shfl_xor(pxk1, 16, 64); pxk1 += __shfl_xor(pxk1, 32, 64);
    if (quad == 0) {
      sRed[0][n][w] = psq0; sRed[1][n][w] = pxh0; sRed[2][n][w] = pxk0;
      if (n < 4) {
        sRed[0][16 + n][w] = psq1; sRed[1][16 + n][w] = pxh1; sRed[2][16 + n][w] = pxk1;
      }
    }
    __syncthreads();  // R2
  }

  // ---- final lam + emit out = lam * h_un from registers ----
  if (t < K_) {
    float ss = 0.0f;
#pragma unroll
    for (int j = 0; j < 8; ++j) ss += sRed[0][t][j];
    sLam[t] = rsqrtf(fmaxf(ss, 1e-12f));
  }
  __syncthreads();
#pragma unroll
  for (int et = 0; et < 2; ++et)
#pragma unroll
    for (int ke = 0; ke < 2; ++ke) {
      const int k = ke * 16 + n;
      if (k < K_) {
        const float lm = sLam[k];
        const int e0 = e0a + 16 * et;
        f32x4 o;
#pragma unroll
        for (int r = 0; r < 4; ++r) o[r] = lm * hReg[et][ke][r];
        *(f32x4*)&out[(size_t)(b * K_ + k) * D_ + e0] = o;
      }
    }
}

extern "C" void kernel_launch(void* const* d_in, const int* in_sizes, int n_in,
                              void* d_out, int out_size, void* d_ws, size_t ws_size,
                              hipStream_t stream) {
  const float* es   = (const float*)d_in[0];
  const int*   mask = (const int*)d_in[1];
  const float* keys = (const float*)d_in[2];
  const float* U    = (const float*)d_in[3];
  const float* V    = (const float*)d_in[4];
  const float* W    = (const float*)d_in[5];
  float* out = (float*)d_out;
  float* XW = (float*)d_ws;  // 134 MB; ws has been sufficient in all passing rounds
  xw_gemm<<<(B_ * S_) / 32, 256, 0, stream>>>(es, W, XW);
  rnn_rec5<<<B_, NT, 0, stream>>>(es, mask, keys, U, V, W, XW, out);
}

// Round 6
// 1119.898 us; speedup vs baseline: 3.7746x; 1.1957x over previous
//
#include <hip/hip_runtime.h>
#include <math.h>

#define B_ 256
#define S_ 512
#define K_ 20
#define D_ 256
#define NT 512
#define LDH 264   // bf16 LDS row stride (shorts)

typedef __attribute__((ext_vector_type(8))) short short8;
typedef __attribute__((ext_vector_type(4))) short short4v;
typedef __attribute__((ext_vector_type(4))) float f32x4;

__device__ __forceinline__ unsigned short rne_bf16(float f) {
  unsigned u = __builtin_bit_cast(unsigned, f);
  u += 0x7FFFu + ((u >> 16) & 1u);
  return (unsigned short)(u >> 16);
}
__device__ __forceinline__ float bf16_to_f32(unsigned short h) {
  return __builtin_bit_cast(float, ((unsigned)h) << 16);
}

// ---------------- Phase A: XW[b,s,:] = es[b,s,:] @ W (R2/R4-proven) ---------
__global__ void xw_gemm(const float* __restrict__ es, const float* __restrict__ W,
                        float* __restrict__ XW) {
  __shared__ float xT[D_ * 36];
  const int t = threadIdx.x;
  const size_t row0 = (size_t)blockIdx.x * 32;
  for (int i = t; i < 32 * D_; i += 256) {
    int rr = i >> 8, d = i & 255;
    xT[d * 36 + rr] = es[row0 * D_ + i];
  }
  __syncthreads();
  float acc[32];
#pragma unroll
  for (int r = 0; r < 32; ++r) acc[r] = 0.0f;
  const float* Wp = W + t;
#pragma unroll 2
  for (int d = 0; d < D_; ++d) {
    float wv = Wp[d * D_];
#pragma unroll
    for (int q = 0; q < 8; ++q) {
      f32x4 xq = *(const f32x4*)&xT[d * 36 + q * 4];
      acc[q * 4 + 0] = fmaf(xq[0], wv, acc[q * 4 + 0]);
      acc[q * 4 + 1] = fmaf(xq[1], wv, acc[q * 4 + 1]);
      acc[q * 4 + 2] = fmaf(xq[2], wv, acc[q * 4 + 2]);
      acc[q * 4 + 3] = fmaf(xq[3], wv, acc[q * 4 + 3]);
    }
  }
  for (int r = 0; r < 32; ++r)
    XW[(row0 + r) * D_ + t] = acc[r];
}

// ---------------- Recurrence: register state, 2-product steady MFMA --------
// Steady loop: hU = (Uhi+Ulo) * bf16(h)  (h-lo term dropped; U stays
// fp32-class via register frags). kV prologue keeps full 3-product.
// lam/g computed redundantly per-wave (lanes 0..19) -> no wave-0 serial chain.
__global__ __launch_bounds__(NT, 2)
void rnn_rec6(const float* __restrict__ es, const int* __restrict__ mask,
              const float* __restrict__ keys, const float* __restrict__ U,
              const float* __restrict__ V, const float* __restrict__ W,
              const float* __restrict__ XW, float* __restrict__ out) {
  __shared__ unsigned short sHhi[32 * LDH];  // rows 0..19 = state, 20..31 stay 0
  __shared__ unsigned short sHlo[32 * LDH];  // prologue (keys) only
  __shared__ float sX[D_];                   // x_{i+1} (gate source)
  __shared__ float sXWb[D_];                 // xW_i (epilogue source)
  __shared__ float sRed[3][K_][9];           // psq / pxh / pxk partials per wave
  __shared__ float sLam[32];                 // final emit only
  __shared__ short sAct[S_];
  __shared__ int   sNact;

  const int b = blockIdx.x, t = threadIdx.x;
  const int w = t >> 6, lane = t & 63, quad = lane >> 4, n = lane & 15;
  const int e0a = (w << 5) + quad * 4;  // et=0 e-base; et adds 16

  // ---- P0: zero mirrors + sRed[0..1]; compact active steps ----
  for (int i = t; i < 32 * LDH; i += NT) { sHhi[i] = 0; sHlo[i] = 0; }
  if (t < 2 * K_ * 9) ((float*)sRed)[t] = 0.0f;
  if (w == 0) {
    int base = 0;
    for (int c = 0; c < 8; ++c) {
      int s = c * 64 + lane;
      int mv = mask[b * S_ + s];
      unsigned long long bal = __ballot(mv != 0);
      int pos = base + (int)__popcll(bal & ((1ull << lane) - 1ull));
      if (mv) sAct[pos] = (short)s;
      base += (int)__popcll(bal);
    }
    if (lane == 0) sNact = base;
  }
  __syncthreads();  // P0

  // keys -> split-bf16 mirrors (rows 0..19)
  for (int i = t; i < K_ * D_; i += NT) {
    int k = i >> 8, d = i & 255;
    float f = keys[(b * K_ + k) * D_ + d];
    unsigned short hi = rne_bf16(f);
    sHhi[k * LDH + d] = hi;
    sHlo[k * LDH + d] = rne_bf16(f - bf16_to_f32(hi));
  }
  // kReg: keys in C/D layout (OOB rows k>=20 -> 0)
  f32x4 kReg[2][2];
#pragma unroll
  for (int et = 0; et < 2; ++et)
#pragma unroll
    for (int ke = 0; ke < 2; ++ke) {
      const int k = ke * 16 + n;
#pragma unroll
      for (int r = 0; r < 4; ++r)
        kReg[et][ke][r] = (k < K_) ? keys[(size_t)(b * K_ + k) * D_ + e0a + 16 * et + r] : 0.0f;
    }

  short8 aHi[8][2], aLo[8][2];  // register-resident A-frags (M^T)
  auto load_A = [&](const float* __restrict__ M) {
#pragma unroll
    for (int kt = 0; kt < 8; ++kt)
#pragma unroll
      for (int et = 0; et < 2; ++et) {
        const int e = ((2 * w + et) << 4) + n;
        const int d0 = kt * 32 + quad * 8;
        short8 h8, l8;
#pragma unroll
        for (int j = 0; j < 8; ++j) {
          float f = M[(d0 + j) * D_ + e];
          unsigned short hi = rne_bf16(f);
          h8[j] = (short)hi;
          l8[j] = (short)rne_bf16(f - bf16_to_f32(hi));
        }
        aHi[kt][et] = h8; aLo[kt][et] = l8;
      }
  };

  // prologue-only: full 3-product (kV must be fp32-faithful)
  auto run_mfma3 = [&](f32x4 acc[2][2]) {
#pragma unroll
    for (int kt = 0; kt < 8; ++kt) {
      short8 bhi[2], blo[2];
#pragma unroll
      for (int ke = 0; ke < 2; ++ke) {
        const int off = (ke * 16 + n) * LDH + kt * 32 + quad * 8;
        bhi[ke] = *(const short8*)&sHhi[off];
        blo[ke] = *(const short8*)&sHlo[off];
      }
#pragma unroll
      for (int et = 0; et < 2; ++et)
#pragma unroll
        for (int ke = 0; ke < 2; ++ke) {
          acc[et][ke] = __builtin_amdgcn_mfma_f32_16x16x32_bf16(aHi[kt][et], bhi[ke], acc[et][ke], 0, 0, 0);
          acc[et][ke] = __builtin_amdgcn_mfma_f32_16x16x32_bf16(aLo[kt][et], bhi[ke], acc[et][ke], 0, 0, 0);
          acc[et][ke] = __builtin_amdgcn_mfma_f32_16x16x32_bf16(aHi[kt][et], blo[ke], acc[et][ke], 0, 0, 0);
        }
    }
  };
  // steady-state: 2-product, hi-mirror only
  auto run_mfma2 = [&](f32x4 acc[2][2]) {
#pragma unroll
    for (int kt = 0; kt < 8; ++kt) {
      short8 bhi[2];
#pragma unroll
      for (int ke = 0; ke < 2; ++ke) {
        const int off = (ke * 16 + n) * LDH + kt * 32 + quad * 8;
        bhi[ke] = *(const short8*)&sHhi[off];
      }
#pragma unroll
      for (int et = 0; et < 2; ++et)
#pragma unroll
        for (int ke = 0; ke < 2; ++ke) {
          acc[et][ke] = __builtin_amdgcn_mfma_f32_16x16x32_bf16(aHi[kt][et], bhi[ke], acc[et][ke], 0, 0, 0);
          acc[et][ke] = __builtin_amdgcn_mfma_f32_16x16x32_bf16(aLo[kt][et], bhi[ke], acc[et][ke], 0, 0, 0);
        }
    }
  };

  load_A(V);
  __syncthreads();  // P1: keys mirrors ready

  f32x4 kvReg[2][2] = {};
  run_mfma3(kvReg);  // kV = keys @ V, register-resident forever
  __syncthreads();  // P2: keys-mirror reads done

  for (int i = t; i < K_ * D_; i += NT) {  // h_un = 0 hi-mirror (lo unused now)
    int k = i >> 8, d = i & 255;
    sHhi[k * LDH + d] = 0;
  }
  load_A(U);
  f32x4 hReg[2][2] = {};
  const int nAct = sNact;
  if (t < D_ && nAct > 0) sX[t] = es[(size_t)(b * S_ + sAct[0]) * D_ + t];
  __syncthreads();  // P3

  // mini-epilogue: pxk = x_0 . keys  (psq=pxh=0 already zeroed)
  {
    float p0 = 0.0f, p1 = 0.0f;
#pragma unroll
    for (int et = 0; et < 2; ++et) {
      f32x4 xq = *(const f32x4*)&sX[e0a + 16 * et];
#pragma unroll
      for (int r = 0; r < 4; ++r) {
        p0 = fmaf(xq[r], kReg[et][0][r], p0);
        p1 = fmaf(xq[r], kReg[et][1][r], p1);
      }
    }
    p0 += __shfl_xor(p0, 16, 64); p0 += __shfl_xor(p0, 32, 64);
    p1 += __shfl_xor(p1, 16, 64); p1 += __shfl_xor(p1, 32, 64);
    if (quad == 0) {
      sRed[2][n][w] = p0;
      if (n < 4) sRed[2][16 + n][w] = p1;
    }
  }
  __syncthreads();  // P4 (acts as the loop's R2)

  // ---- recurrence over active steps ----
  for (int i = 0; i < nAct; ++i) {
    // global prefetch first (hidden under MFMA region)
    float xv = 0.0f, xwv = 0.0f;
    if (t < D_) {
      if (i + 1 < nAct) xv = es[(size_t)(b * S_ + sAct[i + 1]) * D_ + t];
    } else {
      xwv = XW[(size_t)(b * S_ + sAct[i]) * D_ + (t - D_)];
    }
    // lam/g: redundantly computed in every wave (lanes 0..19), then
    // distributed by shuffle -> no cross-wave serial dependency.
    float lamv = 0.0f, gv = 0.0f;
    if (lane < K_) {
      float ss = 0.0f, xh = 0.0f, xk = 0.0f;
#pragma unroll
      for (int j = 0; j < 8; ++j) {
        ss += sRed[0][lane][j]; xh += sRed[1][lane][j]; xk += sRed[2][lane][j];
      }
      lamv = rsqrtf(fmaxf(ss, 1e-12f));
      gv = 1.0f / (1.0f + expf(-(lamv * xh + xk)));
    }
    const float lm0 = __shfl(lamv, n, 64);
    const float g0 = __shfl(gv, n, 64);
    const float lm1s = __shfl(lamv, 16 + n, 64);
    const float g1s = __shfl(gv, 16 + n, 64);

    f32x4 acc[2][2] = {};
    run_mfma2(acc);  // u_{i-1} @ U (2-product)
    if (t < D_) sX[t] = xv; else sXWb[t - D_] = xwv;
    __syncthreads();  // R1

    // epilogue: all register math; write hi-mirror + merged 3-way reduction
    const float lm1 = (n < 4) ? lm1s : 0.0f;
    const float g1 = (n < 4) ? g1s : 0.0f;
    float psq0 = 0.0f, psq1 = 0.0f, pxh0 = 0.0f, pxh1 = 0.0f, pxk0 = 0.0f, pxk1 = 0.0f;
#pragma unroll
    for (int et = 0; et < 2; ++et) {
      const int e0 = e0a + 16 * et;
      f32x4 xw4 = *(const f32x4*)&sXWb[e0];
      f32x4 xn4 = *(const f32x4*)&sX[e0];
      {  // ke = 0 (k = n, always valid)
        f32x4 u; short4v hh;
#pragma unroll
        for (int r = 0; r < 4; ++r) {
          float T = fmaxf(fmaf(lm0, acc[et][0][r], kvReg[et][0][r] + xw4[r]), 0.0f);
          float uv = fmaf(g0, T, lm0 * hReg[et][0][r]);
          u[r] = uv;
          psq0 = fmaf(uv, uv, psq0);
          pxh0 = fmaf(xn4[r], uv, pxh0);
          pxk0 = fmaf(xn4[r], kReg[et][0][r], pxk0);
          hh[r] = (short)rne_bf16(uv);
        }
        hReg[et][0] = u;
        *(short4v*)&sHhi[n * LDH + e0] = hh;
      }
      {  // ke = 1 (k = 16+n, valid for n<4; lm1=g1=0 -> u stays 0 otherwise)
        f32x4 u; short4v hh;
#pragma unroll
        for (int r = 0; r < 4; ++r) {
          float T = fmaxf(fmaf(lm1, acc[et][1][r], kvReg[et][1][r] + xw4[r]), 0.0f);
          float uv = fmaf(g1, T, lm1 * hReg[et][1][r]);
          u[r] = uv;
          psq1 = fmaf(uv, uv, psq1);
          pxh1 = fmaf(xn4[r], uv, pxh1);
          pxk1 = fmaf(xn4[r], kReg[et][1][r], pxk1);
          hh[r] = (short)rne_bf16(uv);
        }
        hReg[et][1] = u;
        if (n < 4) *(short4v*)&sHhi[(16 + n) * LDH + e0] = hh;
      }
    }
    psq0 += __shfl_xor(psq0, 16, 64); psq0 += __shfl_xor(psq0, 32, 64);
    pxh0 += __shfl_xor(pxh0, 16, 64); pxh0 += __shfl_xor(pxh0, 32, 64);
    pxk0 += __shfl_xor(pxk0, 16, 64); pxk0 += __shfl_xor(pxk0, 32, 64);
    psq1 += __shfl_xor(psq1, 16, 64); psq1 += __shfl_xor(psq1, 32, 64);
    pxh1 += __shfl_xor(pxh1, 16, 64); pxh1 += __shfl_xor(pxh1, 32, 64);
    pxk1 += __shfl_xor(pxk1, 16, 64); pxk1 += __shfl_xor(pxk1, 32, 64);
    if (quad == 0) {
      sRed[0][n][w] = psq0; sRed[1][n][w] = pxh0; sRed[2][n][w] = pxk0;
      if (n < 4) {
        sRed[0][16 + n][w] = psq1; sRed[1][16 + n][w] = pxh1; sRed[2][16 + n][w] = pxk1;
      }
    }
    __syncthreads();  // R2
  }

  // ---- final lam + emit out = lam * h_un from registers ----
  if (t < K_) {
    float ss = 0.0f;
#pragma unroll
    for (int j = 0; j < 8; ++j) ss += sRed[0][t][j];
    sLam[t] = rsqrtf(fmaxf(ss, 1e-12f));
  }
  __syncthreads();
#pragma unroll
  for (int et = 0; et < 2; ++et)
#pragma unroll
    for (int ke = 0; ke < 2; ++ke) {
      const int k = ke * 16 + n;
      if (k < K_) {
        const float lm = sLam[k];
        const int e0 = e0a + 16 * et;
        f32x4 o;
#pragma unroll
        for (int r = 0; r < 4; ++r) o[r] = lm * hReg[et][ke][r];
        *(f32x4*)&out[(size_t)(b * K_ + k) * D_ + e0] = o;
      }
    }
}

extern "C" void kernel_launch(void* const* d_in, const int* in_sizes, int n_in,
                              void* d_out, int out_size, void* d_ws, size_t ws_size,
                              hipStream_t stream) {
  const float* es   = (const float*)d_in[0];
  const int*   mask = (const int*)d_in[1];
  const float* keys = (const float*)d_in[2];
  const float* U    = (const float*)d_in[3];
  const float* V    = (const float*)d_in[4];
  const float* W    = (const float*)d_in[5];
  float* out = (float*)d_out;
  float* XW = (float*)d_ws;
  xw_gemm<<<(B_ * S_) / 32, 256, 0, stream>>>(es, W, XW);
  rnn_rec6<<<B_, NT, 0, stream>>>(es, mask, keys, U, V, W, XW, out);
}

// Round 7
// 999.177 us; speedup vs baseline: 4.2307x; 1.1208x over previous
//
#include <hip/hip_runtime.h>
#include <math.h>

#define B_ 256
#define S_ 512
#define K_ 20
#define D_ 256
#define NT 512
#define LDH 264   // bf16 LDS row stride (shorts)

typedef __attribute__((ext_vector_type(8))) short short8;
typedef __attribute__((ext_vector_type(4))) short short4v;
typedef __attribute__((ext_vector_type(4))) float f32x4;

__device__ __forceinline__ unsigned short rne_bf16(float f) {
  unsigned u = __builtin_bit_cast(unsigned, f);
  u += 0x7FFFu + ((u >> 16) & 1u);
  return (unsigned short)(u >> 16);
}
__device__ __forceinline__ float bf16_to_f32(unsigned short h) {
  return __builtin_bit_cast(float, ((unsigned)h) << 16);
}

// ---------------- Phase A: XW = es @ W via MFMA (split-bf16, 3-product) -----
// Pattern-copied from the proven kV prologue: A = W^T register frags,
// B = 32 es-rows staged split-bf16 in LDS. Each WG does 256 rows (8 passes).
__global__ __launch_bounds__(NT, 2)
void xw_mfma(const float* __restrict__ es, const float* __restrict__ W,
             float* __restrict__ XW) {
  __shared__ unsigned short sBhi[32 * LDH];
  __shared__ unsigned short sBlo[32 * LDH];
  const int t = threadIdx.x;
  const int w = t >> 6, lane = t & 63, quad = lane >> 4, n = lane & 15;
  const int e0a = (w << 5) + quad * 4;

  short8 aHi[8][2], aLo[8][2];  // W^T frags: A[m=e][d] = W[d][e]
#pragma unroll
  for (int kt = 0; kt < 8; ++kt)
#pragma unroll
    for (int et = 0; et < 2; ++et) {
      const int e = ((2 * w + et) << 4) + n;
      const int d0 = kt * 32 + quad * 8;
      short8 h8, l8;
#pragma unroll
      for (int j = 0; j < 8; ++j) {
        float f = W[(d0 + j) * D_ + e];
        unsigned short hi = rne_bf16(f);
        h8[j] = (short)hi;
        l8[j] = (short)rne_bf16(f - bf16_to_f32(hi));
      }
      aHi[kt][et] = h8; aLo[kt][et] = l8;
    }

  const size_t rowBase = (size_t)blockIdx.x * 256;
  for (int p = 0; p < 8; ++p) {
    const size_t r0 = rowBase + (size_t)p * 32;
    {  // stage 32 rows -> split bf16 (thread t: row t>>4, cols (t&15)*16..+15)
      const int rr = t >> 4, c0 = (t & 15) * 16;
      const float* src = es + (r0 + rr) * D_ + c0;
#pragma unroll
      for (int h = 0; h < 2; ++h) {
        f32x4 f0 = *(const f32x4*)(src + h * 8);
        f32x4 f1 = *(const f32x4*)(src + h * 8 + 4);
        short8 hh, ll;
#pragma unroll
        for (int j = 0; j < 4; ++j) {
          unsigned short a = rne_bf16(f0[j]);
          hh[j] = (short)a; ll[j] = (short)rne_bf16(f0[j] - bf16_to_f32(a));
          unsigned short bqq = rne_bf16(f1[j]);
          hh[4 + j] = (short)bqq; ll[4 + j] = (short)rne_bf16(f1[j] - bf16_to_f32(bqq));
        }
        *(short8*)&sBhi[rr * LDH + c0 + h * 8] = hh;
        *(short8*)&sBlo[rr * LDH + c0 + h * 8] = ll;
      }
    }
    __syncthreads();
    f32x4 acc[2][2] = {};
#pragma unroll
    for (int kt = 0; kt < 8; ++kt) {
      short8 bhi[2], blo[2];
#pragma unroll
      for (int ke = 0; ke < 2; ++ke) {
        const int off = (ke * 16 + n) * LDH + kt * 32 + quad * 8;
        bhi[ke] = *(const short8*)&sBhi[off];
        blo[ke] = *(const short8*)&sBlo[off];
      }
#pragma unroll
      for (int et = 0; et < 2; ++et)
#pragma unroll
        for (int ke = 0; ke < 2; ++ke) {
          acc[et][ke] = __builtin_amdgcn_mfma_f32_16x16x32_bf16(aHi[kt][et], bhi[ke], acc[et][ke], 0, 0, 0);
          acc[et][ke] = __builtin_amdgcn_mfma_f32_16x16x32_bf16(aLo[kt][et], bhi[ke], acc[et][ke], 0, 0, 0);
          acc[et][ke] = __builtin_amdgcn_mfma_f32_16x16x32_bf16(aHi[kt][et], blo[ke], acc[et][ke], 0, 0, 0);
        }
    }
#pragma unroll
    for (int et = 0; et < 2; ++et)
#pragma unroll
      for (int ke = 0; ke < 2; ++ke)
        *(f32x4*)&XW[(r0 + ke * 16 + n) * D_ + e0a + 16 * et] = acc[et][ke];
    __syncthreads();  // before next pass overwrites staging
  }
}

// ---------------- Recurrence: register state + register x/xW pipelines -----
// x and xW only ever consumed as per-lane f32x4 at e0a+16et -> kept in a
// depth-2 register pipeline loaded straight from global (no LDS staging).
__global__ __launch_bounds__(NT, 2)
void rnn_rec7(const float* __restrict__ es, const int* __restrict__ mask,
              const float* __restrict__ keys, const float* __restrict__ U,
              const float* __restrict__ V, const float* __restrict__ W,
              const float* __restrict__ XW, float* __restrict__ out) {
  __shared__ unsigned short sHhi[32 * LDH];  // rows 0..19 = state, 20..31 stay 0
  __shared__ unsigned short sHlo[32 * LDH];  // prologue (keys) only
  __shared__ float sRed[3][K_][9];           // psq / pxh / pxk partials per wave
  __shared__ float sLam[32];                 // final emit only
  __shared__ short sAct[S_];
  __shared__ int   sNact;

  const int b = blockIdx.x, t = threadIdx.x;
  const int w = t >> 6, lane = t & 63, quad = lane >> 4, n = lane & 15;
  const int e0a = (w << 5) + quad * 4;

  // ---- P0 ----
  for (int i = t; i < 32 * LDH; i += NT) { sHhi[i] = 0; sHlo[i] = 0; }
  if (t < 2 * K_ * 9) ((float*)sRed)[t] = 0.0f;
  if (w == 0) {
    int base = 0;
    for (int c = 0; c < 8; ++c) {
      int s = c * 64 + lane;
      int mv = mask[b * S_ + s];
      unsigned long long bal = __ballot(mv != 0);
      int pos = base + (int)__popcll(bal & ((1ull << lane) - 1ull));
      if (mv) sAct[pos] = (short)s;
      base += (int)__popcll(bal);
    }
    if (lane == 0) sNact = base;
  }
  __syncthreads();  // P0

  for (int i = t; i < K_ * D_; i += NT) {
    int k = i >> 8, d = i & 255;
    float f = keys[(b * K_ + k) * D_ + d];
    unsigned short hi = rne_bf16(f);
    sHhi[k * LDH + d] = hi;
    sHlo[k * LDH + d] = rne_bf16(f - bf16_to_f32(hi));
  }
  f32x4 kReg[2][2];
#pragma unroll
  for (int et = 0; et < 2; ++et)
#pragma unroll
    for (int ke = 0; ke < 2; ++ke) {
      const int k = ke * 16 + n;
#pragma unroll
      for (int r = 0; r < 4; ++r)
        kReg[et][ke][r] = (k < K_) ? keys[(size_t)(b * K_ + k) * D_ + e0a + 16 * et + r] : 0.0f;
    }

  short8 aHi[8][2], aLo[8][2];
  auto load_A = [&](const float* __restrict__ M) {
#pragma unroll
    for (int kt = 0; kt < 8; ++kt)
#pragma unroll
      for (int et = 0; et < 2; ++et) {
        const int e = ((2 * w + et) << 4) + n;
        const int d0 = kt * 32 + quad * 8;
        short8 h8, l8;
#pragma unroll
        for (int j = 0; j < 8; ++j) {
          float f = M[(d0 + j) * D_ + e];
          unsigned short hi = rne_bf16(f);
          h8[j] = (short)hi;
          l8[j] = (short)rne_bf16(f - bf16_to_f32(hi));
        }
        aHi[kt][et] = h8; aLo[kt][et] = l8;
      }
  };
  auto run_mfma3 = [&](f32x4 acc[2][2]) {
#pragma unroll
    for (int kt = 0; kt < 8; ++kt) {
      short8 bhi[2], blo[2];
#pragma unroll
      for (int ke = 0; ke < 2; ++ke) {
        const int off = (ke * 16 + n) * LDH + kt * 32 + quad * 8;
        bhi[ke] = *(const short8*)&sHhi[off];
        blo[ke] = *(const short8*)&sHlo[off];
      }
#pragma unroll
      for (int et = 0; et < 2; ++et)
#pragma unroll
        for (int ke = 0; ke < 2; ++ke) {
          acc[et][ke] = __builtin_amdgcn_mfma_f32_16x16x32_bf16(aHi[kt][et], bhi[ke], acc[et][ke], 0, 0, 0);
          acc[et][ke] = __builtin_amdgcn_mfma_f32_16x16x32_bf16(aLo[kt][et], bhi[ke], acc[et][ke], 0, 0, 0);
          acc[et][ke] = __builtin_amdgcn_mfma_f32_16x16x32_bf16(aHi[kt][et], blo[ke], acc[et][ke], 0, 0, 0);
        }
    }
  };
  auto run_mfma2 = [&](f32x4 acc[2][2]) {
#pragma unroll
    for (int kt = 0; kt < 8; ++kt) {
      short8 bhi[2];
#pragma unroll
      for (int ke = 0; ke < 2; ++ke) {
        const int off = (ke * 16 + n) * LDH + kt * 32 + quad * 8;
        bhi[ke] = *(const short8*)&sHhi[off];
      }
#pragma unroll
      for (int et = 0; et < 2; ++et)
#pragma unroll
        for (int ke = 0; ke < 2; ++ke) {
          acc[et][ke] = __builtin_amdgcn_mfma_f32_16x16x32_bf16(aHi[kt][et], bhi[ke], acc[et][ke], 0, 0, 0);
          acc[et][ke] = __builtin_amdgcn_mfma_f32_16x16x32_bf16(aLo[kt][et], bhi[ke], acc[et][ke], 0, 0, 0);
        }
    }
  };

  load_A(V);
  __syncthreads();  // P1

  f32x4 kvReg[2][2] = {};
  run_mfma3(kvReg);
  __syncthreads();  // P2

  for (int i = t; i < K_ * D_; i += NT) {
    int k = i >> 8, d = i & 255;
    sHhi[k * LDH + d] = 0;
  }
  load_A(U);
  f32x4 hReg[2][2] = {};
  const int nAct = sNact;

  // register pipelines: consume-slots for epilogue 0
  f32x4 xEc[2] = {}, xwEc[2] = {};
  if (nAct > 0) {
    const int s1 = sAct[(nAct > 1) ? 1 : 0];
    const int s0 = sAct[0];
#pragma unroll
    for (int et = 0; et < 2; ++et) {
      xEc[et]  = *(const f32x4*)&es[(size_t)(b * S_ + s1) * D_ + e0a + 16 * et];
      xwEc[et] = *(const f32x4*)&XW[(size_t)(b * S_ + s0) * D_ + e0a + 16 * et];
    }
  }
  __syncthreads();  // P3: h mirrors zeroed

  // mini-epilogue: pxk = x_0 . keys (direct per-lane global reads)
  if (nAct > 0) {
    const int s0 = sAct[0];
    float p0 = 0.0f, p1 = 0.0f;
#pragma unroll
    for (int et = 0; et < 2; ++et) {
      f32x4 xq = *(const f32x4*)&es[(size_t)(b * S_ + s0) * D_ + e0a + 16 * et];
#pragma unroll
      for (int r = 0; r < 4; ++r) {
        p0 = fmaf(xq[r], kReg[et][0][r], p0);
        p1 = fmaf(xq[r], kReg[et][1][r], p1);
      }
    }
    p0 += __shfl_xor(p0, 16, 64); p0 += __shfl_xor(p0, 32, 64);
    p1 += __shfl_xor(p1, 16, 64); p1 += __shfl_xor(p1, 32, 64);
    if (quad == 0) {
      sRed[2][n][w] = p0;
      if (n < 4) sRed[2][16 + n][w] = p1;
    }
  } else if (quad == 0) {
    sRed[2][n][w] = 0.0f;
    if (n < 4) sRed[2][16 + n][w] = 0.0f;
  }
  __syncthreads();  // P4 (loop's R2)

  // ---- recurrence ----
  for (int i = 0; i < nAct; ++i) {
    // issue next-slot loads (consumed in epilogue of step i+1)
    const int iX = (i + 2 < nAct) ? i + 2 : nAct - 1;
    const int iW = (i + 1 < nAct) ? i + 1 : nAct - 1;
    const size_t rX = (size_t)(b * S_ + sAct[iX]) * D_;
    const size_t rW = (size_t)(b * S_ + sAct[iW]) * D_;
    f32x4 xEn[2], xwEn[2];
#pragma unroll
    for (int et = 0; et < 2; ++et) {
      xEn[et]  = *(const f32x4*)&es[rX + e0a + 16 * et];
      xwEn[et] = *(const f32x4*)&XW[rW + e0a + 16 * et];
    }
    // lam/g redundantly per wave (lanes 0..19)
    float lamv = 0.0f, gv = 0.0f;
    if (lane < K_) {
      float ss = 0.0f, xh = 0.0f, xk = 0.0f;
#pragma unroll
      for (int j = 0; j < 8; ++j) {
        ss += sRed[0][lane][j]; xh += sRed[1][lane][j]; xk += sRed[2][lane][j];
      }
      lamv = rsqrtf(fmaxf(ss, 1e-12f));
      gv = 1.0f / (1.0f + expf(-(lamv * xh + xk)));
    }
    const float lm0 = __shfl(lamv, n, 64);
    const float g0 = __shfl(gv, n, 64);
    const float lm1s = __shfl(lamv, 16 + n, 64);
    const float g1s = __shfl(gv, 16 + n, 64);

    f32x4 acc[2][2] = {};
    run_mfma2(acc);
    __syncthreads();  // R1: all mirror reads done

    const float lm1 = (n < 4) ? lm1s : 0.0f;
    const float g1 = (n < 4) ? g1s : 0.0f;
    float psq0 = 0.0f, psq1 = 0.0f, pxh0 = 0.0f, pxh1 = 0.0f, pxk0 = 0.0f, pxk1 = 0.0f;
#pragma unroll
    for (int et = 0; et < 2; ++et) {
      const int e0 = e0a + 16 * et;
      f32x4 xw4 = xwEc[et];
      f32x4 xn4 = xEc[et];
      {  // ke=0
        f32x4 u; short4v hh;
#pragma unroll
        for (int r = 0; r < 4; ++r) {
          float T = fmaxf(fmaf(lm0, acc[et][0][r], kvReg[et][0][r] + xw4[r]), 0.0f);
          float uv = fmaf(g0, T, lm0 * hReg[et][0][r]);
          u[r] = uv;
          psq0 = fmaf(uv, uv, psq0);
          pxh0 = fmaf(xn4[r], uv, pxh0);
          pxk0 = fmaf(xn4[r], kReg[et][0][r], pxk0);
          hh[r] = (short)rne_bf16(uv);
        }
        hReg[et][0] = u;
        *(short4v*)&sHhi[n * LDH + e0] = hh;
      }
      {  // ke=1
        f32x4 u; short4v hh;
#pragma unroll
        for (int r = 0; r < 4; ++r) {
          float T = fmaxf(fmaf(lm1, acc[et][1][r], kvReg[et][1][r] + xw4[r]), 0.0f);
          float uv = fmaf(g1, T, lm1 * hReg[et][1][r]);
          u[r] = uv;
          psq1 = fmaf(uv, uv, psq1);
          pxh1 = fmaf(xn4[r], uv, pxh1);
          pxk1 = fmaf(xn4[r], kReg[et][1][r], pxk1);
          hh[r] = (short)rne_bf16(uv);
        }
        hReg[et][1] = u;
        if (n < 4) *(short4v*)&sHhi[(16 + n) * LDH + e0] = hh;
      }
    }
    psq0 += __shfl_xor(psq0, 16, 64); psq0 += __shfl_xor(psq0, 32, 64);
    pxh0 += __shfl_xor(pxh0, 16, 64); pxh0 += __shfl_xor(pxh0, 32, 64);
    pxk0 += __shfl_xor(pxk0, 16, 64); pxk0 += __shfl_xor(pxk0, 32, 64);
    psq1 += __shfl_xor(psq1, 16, 64); psq1 += __shfl_xor(psq1, 32, 64);
    pxh1 += __shfl_xor(pxh1, 16, 64); pxh1 += __shfl_xor(pxh1, 32, 64);
    pxk1 += __shfl_xor(pxk1, 16, 64); pxk1 += __shfl_xor(pxk1, 32, 64);
    if (quad == 0) {
      sRed[0][n][w] = psq0; sRed[1][n][w] = pxh0; sRed[2][n][w] = pxk0;
      if (n < 4) {
        sRed[0][16 + n][w] = psq1; sRed[1][16 + n][w] = pxh1; sRed[2][16 + n][w] = pxk1;
      }
    }
    // rotate pipelines
#pragma unroll
    for (int et = 0; et < 2; ++et) { xEc[et] = xEn[et]; xwEc[et] = xwEn[et]; }
    __syncthreads();  // R2
  }

  // ---- final lam + emit ----
  if (t < K_) {
    float ss = 0.0f;
#pragma unroll
    for (int j = 0; j < 8; ++j) ss += sRed[0][t][j];
    sLam[t] = rsqrtf(fmaxf(ss, 1e-12f));
  }
  __syncthreads();
#pragma unroll
  for (int et = 0; et < 2; ++et)
#pragma unroll
    for (int ke = 0; ke < 2; ++ke) {
      const int k = ke * 16 + n;
      if (k < K_) {
        const float lm = sLam[k];
        const int e0 = e0a + 16 * et;
        f32x4 o;
#pragma unroll
        for (int r = 0; r < 4; ++r) o[r] = lm * hReg[et][ke][r];
        *(f32x4*)&out[(size_t)(b * K_ + k) * D_ + e0] = o;
      }
    }
}

extern "C" void kernel_launch(void* const* d_in, const int* in_sizes, int n_in,
                              void* d_out, int out_size, void* d_ws, size_t ws_size,
                              hipStream_t stream) {
  const float* es   = (const float*)d_in[0];
  const int*   mask = (const int*)d_in[1];
  const float* keys = (const float*)d_in[2];
  const float* U    = (const float*)d_in[3];
  const float* V    = (const float*)d_in[4];
  const float* W    = (const float*)d_in[5];
  float* out = (float*)d_out;
  float* XW = (float*)d_ws;  // 134 MB scratch (sufficient in all rounds)
  xw_mfma<<<(B_ * S_) / 256, NT, 0, stream>>>(es, W, XW);
  rnn_rec7<<<B_, NT, 0, stream>>>(es, mask, keys, U, V, W, XW, out);
}